// Round 1
// baseline (122.199 us; speedup 1.0000x reference)
//
#include <hip/hip_runtime.h>
#include <hip/hip_bf16.h>
#include <stdint.h>
#include <stddef.h>

// Problem constants
#define NIMG 32
#define C_IN 128
#define C_OUT 256
#define HW 56
#define SP 3136            // 56*56
#define STOT (NIMG * SP)   // 100352
#define PD 58              // padded spatial dim
#define KTOT 1152          // 128*9

// GEMM tiling
#define BM 128
#define BN 128
#define BK 32
#define NKT (KTOT / BK)    // 36

typedef __attribute__((ext_vector_type(8))) short bf16x8;
typedef __attribute__((ext_vector_type(4))) float f32x4;

__device__ __forceinline__ void gload16(const void* g, void* l) {
    __builtin_amdgcn_global_load_lds(
        (const __attribute__((address_space(1))) void*)g,
        (__attribute__((address_space(3))) void*)l,
        16, 0, 0);
}

// ---------------------------------------------------------------------------
// Prepass 1: NCHW fp32 -> padded NHWC bf16  [n][58][58][128], zero border.
// Border is zeroed by a hipMemsetAsync before this kernel.
// Block: 256 threads. Grid: 56(h) * 32(n) * 4(ci-tiles of 32).
// ---------------------------------------------------------------------------
__global__ void pad_transpose_kernel(const float* __restrict__ x,
                                     __hip_bfloat16* __restrict__ xp) {
    __shared__ float t[32][57];  // +1 pad: conflict-free transpose reads
    int b = blockIdx.x;
    int h   = b % HW;
    int n   = (b / HW) % NIMG;
    int ci0 = (b / (HW * NIMG)) * 32;

    for (int idx = threadIdx.x; idx < 32 * HW; idx += 256) {
        int ci = idx / HW, w = idx - ci * HW;
        t[ci][w] = x[(((size_t)n * C_IN + ci0 + ci) * HW + h) * HW + w];
    }
    __syncthreads();
    for (int idx = threadIdx.x; idx < HW * 32; idx += 256) {
        int w = idx >> 5, ci = idx & 31;
        xp[(((size_t)n * PD + h + 1) * PD + (w + 1)) * C_IN + ci0 + ci] =
            __float2bfloat16(t[ci][w]);
    }
}

// ---------------------------------------------------------------------------
// Prepass 2: weight OIHW fp32 -> [tap][co][ci] bf16, tap = kh*3+kw
// ---------------------------------------------------------------------------
__global__ void wt_transform_kernel(const float* __restrict__ wgt,
                                    __hip_bfloat16* __restrict__ wt) {
    int idx = blockIdx.x * 256 + threadIdx.x;     // 9*256*128 = 294912 exact
    int ci  = idx & 127;
    int co  = (idx >> 7) & 255;
    int tap = idx >> 15;
    wt[idx] = __float2bfloat16(wgt[(co * C_IN + ci) * 9 + tap]);
}

// ---------------------------------------------------------------------------
// Main: implicit GEMM. C[co][s] = sum_{tap,ci} W[tap][co][ci] * Xp[s+tap][ci]
// 128x128 tile, BK=32, 4 waves each owning 64x64, mfma_f32_16x16x32_bf16.
// A_lds[co][ci], B_lds[s][ci] (both K-contiguous -> ds_read_b128 frags).
// ---------------------------------------------------------------------------
__global__ __launch_bounds__(256, 2)
void conv_mfma_kernel(const __hip_bfloat16* __restrict__ xp,
                      const __hip_bfloat16* __restrict__ wt,
                      const float* __restrict__ bias,
                      float* __restrict__ out) {
    __shared__ __align__(16) __hip_bfloat16 Asm[BM * BK];  // 8 KB
    __shared__ __align__(16) __hip_bfloat16 Bsm[BN * BK];  // 8 KB

    const int tid  = threadIdx.x;
    const int lane = tid & 63;
    const int wid  = tid >> 6;
    const int s0   = blockIdx.x * BN;
    const int co0  = blockIdx.y * BM;

    // --- staging precompute: each thread stages 2 A-rows + 2 B-rows ---
    // round r: row = r*64 + wid*16 + (lane>>2); 16B chunk = lane&3
    const int chunk = lane & 3;
    int bbase[2];   // element offset of px[h][w] for this B-row
    int arow[2];    // global co of this A-row
    #pragma unroll
    for (int r = 0; r < 2; ++r) {
        int row = r * 64 + wid * 16 + (lane >> 2);
        int s   = s0 + row;
        int n   = s / SP;
        int rem = s - n * SP;
        int h   = rem / HW;
        int w   = rem - h * HW;
        bbase[r] = ((n * PD + h) * PD + w) * C_IN;
        arow[r]  = co0 + row;
    }

    // --- compute-phase layout ---
    const int wm = (wid >> 1) * 64;    // wave m (co) base within tile
    const int wn = (wid & 1) * 64;     // wave n (spatial) base within tile
    const int aoff0 = (wm + (lane & 15)) * BK + (lane >> 4) * 8;
    const int boff0 = (wn + (lane & 15)) * BK + (lane >> 4) * 8;

    f32x4 acc[4][4] = {};

    for (int kt = 0; kt < NKT; ++kt) {
        const int tap = kt >> 2;              // 0..8
        const int ci0 = (kt & 3) << 5;        // 0,32,64,96
        const int kh  = tap / 3;
        const int kw  = tap - kh * 3;
        const int boffg = (kh * PD + kw) * C_IN + ci0 + chunk * 8;
        const int aoffg = tap * C_OUT * C_IN + ci0 + chunk * 8;

        __syncthreads();   // previous compute done before overwrite
        #pragma unroll
        for (int r = 0; r < 2; ++r) {
            gload16(wt + aoffg + arow[r] * C_IN, &Asm[(r * 4 + wid) * 512]);
            gload16(xp + bbase[r] + boffg,       &Bsm[(r * 4 + wid) * 512]);
        }
        __syncthreads();   // drains vmcnt: staged tiles visible

        bf16x8 a[4], b[4];
        #pragma unroll
        for (int mi = 0; mi < 4; ++mi)
            a[mi] = *(const bf16x8*)&Asm[aoff0 + mi * 16 * BK];
        #pragma unroll
        for (int ni = 0; ni < 4; ++ni)
            b[ni] = *(const bf16x8*)&Bsm[boff0 + ni * 16 * BK];
        #pragma unroll
        for (int mi = 0; mi < 4; ++mi)
            #pragma unroll
            for (int ni = 0; ni < 4; ++ni)
                acc[mi][ni] = __builtin_amdgcn_mfma_f32_16x16x32_bf16(
                    a[mi], b[ni], acc[mi][ni], 0, 0, 0);
    }

    // --- epilogue: D col = spatial (lane&15), row = co ((lane>>4)*4 + r) ---
    #pragma unroll
    for (int ni = 0; ni < 4; ++ni) {
        int s  = s0 + wn + ni * 16 + (lane & 15);
        int n  = s / SP;
        int si = s - n * SP;
        #pragma unroll
        for (int mi = 0; mi < 4; ++mi) {
            int cob = co0 + wm + mi * 16 + ((lane >> 4) << 2);
            #pragma unroll
            for (int r = 0; r < 4; ++r) {
                int co = cob + r;
                out[((size_t)(n * C_OUT + co)) * SP + si] =
                    acc[mi][ni][r] + bias[co];
            }
        }
    }
}

// ---------------------------------------------------------------------------
// Fallback: direct fp32 conv (used only if ws is too small). Slow but correct.
// ---------------------------------------------------------------------------
__global__ void conv_direct_kernel(const float* __restrict__ x,
                                   const float* __restrict__ wgt,
                                   const float* __restrict__ bias,
                                   float* __restrict__ out) {
    long idx = (long)blockIdx.x * 256 + threadIdx.x;
    if (idx >= (long)NIMG * C_OUT * SP) return;
    int si = (int)(idx % SP);
    int co = (int)((idx / SP) % C_OUT);
    int n  = (int)(idx / ((long)SP * C_OUT));
    int h = si / HW, w = si - (si / HW) * HW;
    float acc = bias[co];
    for (int ci = 0; ci < C_IN; ++ci) {
        const float* xr = x + ((size_t)n * C_IN + ci) * SP;
        const float* wr = wgt + ((size_t)co * C_IN + ci) * 9;
        #pragma unroll
        for (int kh = 0; kh < 3; ++kh) {
            int ih = h + kh - 1;
            if (ih < 0 || ih >= HW) continue;
            #pragma unroll
            for (int kw = 0; kw < 3; ++kw) {
                int iw = w + kw - 1;
                if (iw < 0 || iw >= HW) continue;
                acc += xr[ih * HW + iw] * wr[kh * 3 + kw];
            }
        }
    }
    out[idx] = acc;
}

// ---------------------------------------------------------------------------
extern "C" void kernel_launch(void* const* d_in, const int* in_sizes, int n_in,
                              void* d_out, int out_size, void* d_ws, size_t ws_size,
                              hipStream_t stream) {
    const float* x    = (const float*)d_in[0];
    const float* wgt  = (const float*)d_in[1];
    const float* bias = (const float*)d_in[2];
    float* out = (float*)d_out;

    const size_t xp_bytes = (size_t)NIMG * PD * PD * C_IN * sizeof(__hip_bfloat16); // 27,557,888
    const size_t wt_bytes = (size_t)9 * C_OUT * C_IN * sizeof(__hip_bfloat16);      // 589,824

    if (ws_size >= xp_bytes + wt_bytes) {
        __hip_bfloat16* xp = (__hip_bfloat16*)d_ws;
        __hip_bfloat16* wt = (__hip_bfloat16*)((char*)d_ws + xp_bytes);

        hipMemsetAsync(d_ws, 0, xp_bytes, stream);  // zero padded borders
        pad_transpose_kernel<<<HW * NIMG * 4, 256, 0, stream>>>(x, xp);
        wt_transform_kernel<<<(9 * C_OUT * C_IN) / 256, 256, 0, stream>>>(wgt, wt);

        dim3 grid(STOT / BN, C_OUT / BM);  // (784, 2)
        conv_mfma_kernel<<<grid, 256, 0, stream>>>(xp, wt, bias, out);
    } else {
        long total = (long)NIMG * C_OUT * SP;
        conv_direct_kernel<<<(int)((total + 255) / 256), 256, 0, stream>>>(
            x, wgt, bias, out);
    }
}

// Round 2
// 103.363 us; speedup vs baseline: 1.1822x; 1.1822x over previous
//
#include <hip/hip_runtime.h>
#include <hip/hip_bf16.h>
#include <stdint.h>
#include <stddef.h>

// Problem constants
#define NIMG 32
#define C_IN 128
#define C_OUT 256
#define HW 56
#define SP 3136            // 56*56
#define STOT (NIMG * SP)   // 100352
#define PD 58              // padded spatial dim
#define KTOT 1152          // 128*9

// GEMM tiling (8-phase 256^2 template)
#define BM 256
#define BN 256
#define BK 64
#define NKT (KTOT / BK)    // 18 K-tiles
#define THREADS 512

typedef __attribute__((ext_vector_type(8))) short bf16x8;
typedef __attribute__((ext_vector_type(4))) float f32x4;

__device__ __forceinline__ void gload16(const void* g, void* l) {
    __builtin_amdgcn_global_load_lds(
        (const __attribute__((address_space(1))) void*)g,
        (__attribute__((address_space(3))) void*)l,
        16, 0, 0);
}

#define BAR() do { asm volatile("" ::: "memory"); \
                   __builtin_amdgcn_s_barrier();  \
                   asm volatile("" ::: "memory"); } while (0)
#define LGKM0() do { asm volatile("s_waitcnt lgkmcnt(0)" ::: "memory"); \
                     __builtin_amdgcn_sched_barrier(0); } while (0)
#define VMCNT(n) do { asm volatile("s_waitcnt vmcnt(" #n ")" ::: "memory"); \
                      __builtin_amdgcn_sched_barrier(0); } while (0)

__device__ __forceinline__ unsigned short bf2u(float f) {
    __hip_bfloat16 b = __float2bfloat16(f);
    return *reinterpret_cast<unsigned short*>(&b);
}

// ---------------------------------------------------------------------------
// Prepass 1: NCHW fp32 -> padded NHWC bf16 [n][58][58][128], borders zeroed
// inline (no memset pass). One block per (n, padded row hp).
// ---------------------------------------------------------------------------
__global__ __launch_bounds__(256)
void pad_transpose_kernel(const float* __restrict__ x,
                          __hip_bfloat16* __restrict__ xp) {
    __shared__ float t[C_IN][HW + 1];
    const int hp = blockIdx.x % PD;
    const int n  = blockIdx.x / PD;
    const int h  = hp - 1;
    const bool interior = ((unsigned)h < (unsigned)HW);
    if (interior) {
        for (int idx = threadIdx.x; idx < C_IN * HW; idx += 256) {
            int ci = idx / HW, w = idx - ci * HW;
            t[ci][w] = x[((size_t)n * C_IN + ci) * SP + h * HW + w];
        }
    }
    __syncthreads();
    ushort4* dst = (ushort4*)(xp + ((size_t)n * PD + hp) * PD * C_IN);
    for (int idx = threadIdx.x; idx < PD * C_IN / 4; idx += 256) {
        int el = idx * 4;
        int wp = el >> 7, c0 = el & 127;
        ushort4 v = {0, 0, 0, 0};
        if (interior && wp >= 1 && wp <= HW) {
            int w = wp - 1;
            v.x = bf2u(t[c0 + 0][w]);
            v.y = bf2u(t[c0 + 1][w]);
            v.z = bf2u(t[c0 + 2][w]);
            v.w = bf2u(t[c0 + 3][w]);
        }
        dst[idx] = v;
    }
}

// ---------------------------------------------------------------------------
// Prepass 2: weight OIHW fp32 -> [tap][co][ci] bf16, tap = kh*3+kw
// ---------------------------------------------------------------------------
__global__ void wt_transform_kernel(const float* __restrict__ wgt,
                                    __hip_bfloat16* __restrict__ wt) {
    int idx = blockIdx.x * 256 + threadIdx.x;     // 9*256*128 = 294912 exact
    int ci  = idx & 127;
    int co  = (idx >> 7) & 255;
    int tap = idx >> 15;
    wt[idx] = __float2bfloat16(wgt[(co * C_IN + ci) * 9 + tap]);
}

// ---------------------------------------------------------------------------
// Main: implicit GEMM, 256x256 tile, BK=64, 8 waves, 8-phase schedule with
// counted vmcnt (T3+T4), LDS chunk-XOR swizzle (T2), setprio (T5).
// LDS regions (shorts): A(b,kk) = b*32768 + kk*8192 ; B(b,kk) = +16384.
// Each region: [256 rows][32 ci] bf16, row = 64B.
// Stagger (during tile t, buf b): p0: (t+1,A,k1)->b^1  p1: (t+1,B,k1)->b^1
//                                 p2: (t+2,A,k0)->b    p3: (t+2,B,k0)->b
// Every target region is barrier-retired before its staging issue.
// vmcnt(4) at end of p3 forces tile t+1 fully landed; 2 half-tiles in flight.
// ---------------------------------------------------------------------------
__global__ __launch_bounds__(THREADS, 2)
void conv_mfma_kernel(const __hip_bfloat16* __restrict__ xp,
                      const __hip_bfloat16* __restrict__ wt,
                      const float* __restrict__ bias,
                      float* __restrict__ out) {
    extern __shared__ short smem[];   // 2*2*2*8192 shorts = 128 KiB

    const int tid  = threadIdx.x;
    const int lane = tid & 63;
    const int wid  = tid >> 6;
    const int s0   = blockIdx.x * BN;

    // ---- staging constants (inverse-swizzled global source, rule #21) ----
    const int cg_el = (((lane & 3) ^ ((lane >> 3) & 3)) << 3);  // chunk XOR
    const int srow  = wid * 16 + (lane >> 2);                   // row in half
    const int aS0   = srow * C_IN + cg_el;                      // A row r=0
    const int aS1   = aS0 + 128 * C_IN;                         // A row r=1
    int s_r = s0 + srow;
    int n_  = s_r / SP, rem = s_r - n_ * SP;
    int h_  = rem / HW, w_ = rem - h_ * HW;
    const int bS0 = ((n_ * PD + h_) * PD + w_) * C_IN + cg_el;
    s_r += 128;
    n_ = s_r / SP; rem = s_r - n_ * SP; h_ = rem / HW; w_ = rem - h_ * HW;
    const int bS1 = ((n_ * PD + h_) * PD + w_) * C_IN + cg_el;
    const int ldsw = wid * 512;   // wave-uniform LDS dest (elements)

    // ---- compute-phase read offsets (swizzled) ----
    const int rl  = lane & 15;
    const int rch = (((lane >> 4) ^ ((lane >> 1) & 3)) << 3);
    const int wm  = (wid >> 2) * 128;   // 2 M-waves
    const int wn  = (wid & 3) * 64;     // 4 N-waves
    const int aRd = (wm + rl) * 32 + rch;
    const int bRd = (wn + rl) * 32 + rch;

    auto STG_A = [&](int kt, int kk, int bf) {
        int t2 = (kt >= NKT) ? kt - NKT : kt;
        int tap = t2 >> 1;
        const __hip_bfloat16* src =
            wt + tap * (C_OUT * C_IN) + ((t2 & 1) << 6) + (kk << 5);
        short* d = smem + bf * 32768 + kk * 8192 + ldsw;
        gload16(src + aS0, d);
        gload16(src + aS1, d + 4096);
    };
    auto STG_B = [&](int kt, int kk, int bf) {
        int t2 = (kt >= NKT) ? kt - NKT : kt;
        int tap = t2 >> 1;
        int kh = (tap * 11) >> 5, kw = tap - kh * 3;
        const __hip_bfloat16* src =
            xp + (kh * PD + kw) * C_IN + ((t2 & 1) << 6) + (kk << 5);
        short* d = smem + bf * 32768 + 16384 + kk * 8192 + ldsw;
        gload16(src + bS0, d);
        gload16(src + bS1, d + 4096);
    };

    f32x4 acc[8][4] = {};

    // ---- prologue: tile0 full + tile1 k0 halves; vmcnt(4) -> tile0 ready --
    STG_A(0, 0, 0); STG_B(0, 0, 0);
    STG_A(0, 1, 0); STG_B(0, 1, 0);
    STG_A(1, 0, 1); STG_B(1, 0, 1);
    VMCNT(4);
    BAR();

    for (int t = 0; t < NKT; ++t) {
        const int b = t & 1;
        const short* Ak0 = smem + b * 32768;
        const short* Ak1 = Ak0 + 8192;
        const short* Bk0 = Ak0 + 16384;
        const short* Bk1 = Ak0 + 24576;
        bf16x8 af[4], bfr[4];

        // ---- phase 0: kk0, wave-rows 0-63 ----
        #pragma unroll
        for (int j = 0; j < 4; ++j) af[j]  = *(const bf16x8*)(Ak0 + aRd + j * 512);
        #pragma unroll
        for (int j = 0; j < 4; ++j) bfr[j] = *(const bf16x8*)(Bk0 + bRd + j * 512);
        STG_A(t + 1, 1, b ^ 1);
        BAR(); LGKM0();
        __builtin_amdgcn_s_setprio(1);
        #pragma unroll
        for (int mi = 0; mi < 4; ++mi)
            #pragma unroll
            for (int ni = 0; ni < 4; ++ni)
                acc[mi][ni] = __builtin_amdgcn_mfma_f32_16x16x32_bf16(
                    af[mi], bfr[ni], acc[mi][ni], 0, 0, 0);
        __builtin_amdgcn_s_setprio(0);
        BAR();

        // ---- phase 1: kk0, wave-rows 64-127 ----
        #pragma unroll
        for (int j = 0; j < 4; ++j) af[j] = *(const bf16x8*)(Ak0 + aRd + 2048 + j * 512);
        STG_B(t + 1, 1, b ^ 1);
        BAR(); LGKM0();
        __builtin_amdgcn_s_setprio(1);
        #pragma unroll
        for (int mi = 0; mi < 4; ++mi)
            #pragma unroll
            for (int ni = 0; ni < 4; ++ni)
                acc[4 + mi][ni] = __builtin_amdgcn_mfma_f32_16x16x32_bf16(
                    af[mi], bfr[ni], acc[4 + mi][ni], 0, 0, 0);
        __builtin_amdgcn_s_setprio(0);
        BAR();

        // ---- phase 2: kk1, wave-rows 0-63 ----
        #pragma unroll
        for (int j = 0; j < 4; ++j) af[j]  = *(const bf16x8*)(Ak1 + aRd + j * 512);
        #pragma unroll
        for (int j = 0; j < 4; ++j) bfr[j] = *(const bf16x8*)(Bk1 + bRd + j * 512);
        STG_A(t + 2, 0, b);
        BAR(); LGKM0();
        __builtin_amdgcn_s_setprio(1);
        #pragma unroll
        for (int mi = 0; mi < 4; ++mi)
            #pragma unroll
            for (int ni = 0; ni < 4; ++ni)
                acc[mi][ni] = __builtin_amdgcn_mfma_f32_16x16x32_bf16(
                    af[mi], bfr[ni], acc[mi][ni], 0, 0, 0);
        __builtin_amdgcn_s_setprio(0);
        BAR();

        // ---- phase 3: kk1, wave-rows 64-127 ----
        #pragma unroll
        for (int j = 0; j < 4; ++j) af[j] = *(const bf16x8*)(Ak1 + aRd + 2048 + j * 512);
        STG_B(t + 2, 0, b);
        BAR(); LGKM0();
        __builtin_amdgcn_s_setprio(1);
        #pragma unroll
        for (int mi = 0; mi < 4; ++mi)
            #pragma unroll
            for (int ni = 0; ni < 4; ++ni)
                acc[4 + mi][ni] = __builtin_amdgcn_mfma_f32_16x16x32_bf16(
                    af[mi], bfr[ni], acc[4 + mi][ni], 0, 0, 0);
        __builtin_amdgcn_s_setprio(0);
        VMCNT(4);          // tile t+1 fully landed; 2 half-tiles stay in flight
        BAR();
    }

    // ---- epilogue: D col = spatial (lane&15), row = co ----
    #pragma unroll
    for (int ni = 0; ni < 4; ++ni) {
        int s  = s0 + wn + ni * 16 + rl;
        int n  = s / SP;
        int si = s - n * SP;
        float* obase = out + (size_t)n * C_OUT * SP + si;
        #pragma unroll
        for (int mi = 0; mi < 8; ++mi) {
            int cob = wm + mi * 16 + ((lane >> 4) << 2);
            #pragma unroll
            for (int j = 0; j < 4; ++j) {
                int co = cob + j;
                obase[(size_t)co * SP] = acc[mi][ni][j] + bias[co];
            }
        }
    }
}

// ---------------------------------------------------------------------------
// Fallback: direct fp32 conv (only if ws too small). Slow but correct.
// ---------------------------------------------------------------------------
__global__ void conv_direct_kernel(const float* __restrict__ x,
                                   const float* __restrict__ wgt,
                                   const float* __restrict__ bias,
                                   float* __restrict__ out) {
    long idx = (long)blockIdx.x * 256 + threadIdx.x;
    if (idx >= (long)NIMG * C_OUT * SP) return;
    int si = (int)(idx % SP);
    int co = (int)((idx / SP) % C_OUT);
    int n  = (int)(idx / ((long)SP * C_OUT));
    int h = si / HW, w = si - (si / HW) * HW;
    float acc = bias[co];
    for (int ci = 0; ci < C_IN; ++ci) {
        const float* xr = x + ((size_t)n * C_IN + ci) * SP;
        const float* wr = wgt + ((size_t)co * C_IN + ci) * 9;
        #pragma unroll
        for (int kh = 0; kh < 3; ++kh) {
            int ih = h + kh - 1;
            if (ih < 0 || ih >= HW) continue;
            #pragma unroll
            for (int kw = 0; kw < 3; ++kw) {
                int iw = w + kw - 1;
                if (iw < 0 || iw >= HW) continue;
                acc += xr[ih * HW + iw] * wr[kh * 3 + kw];
            }
        }
    }
    out[idx] = acc;
}

// ---------------------------------------------------------------------------
extern "C" void kernel_launch(void* const* d_in, const int* in_sizes, int n_in,
                              void* d_out, int out_size, void* d_ws, size_t ws_size,
                              hipStream_t stream) {
    const float* x    = (const float*)d_in[0];
    const float* wgt  = (const float*)d_in[1];
    const float* bias = (const float*)d_in[2];
    float* out = (float*)d_out;

    const size_t xp_bytes = (size_t)NIMG * PD * PD * C_IN * sizeof(__hip_bfloat16);
    const size_t wt_bytes = (size_t)9 * C_OUT * C_IN * sizeof(__hip_bfloat16);

    if (ws_size >= xp_bytes + wt_bytes) {
        __hip_bfloat16* xp  = (__hip_bfloat16*)d_ws;
        __hip_bfloat16* wtb = (__hip_bfloat16*)((char*)d_ws + xp_bytes);

        pad_transpose_kernel<<<NIMG * PD, 256, 0, stream>>>(x, xp);
        wt_transform_kernel<<<(9 * C_OUT * C_IN) / 256, 256, 0, stream>>>(wgt, wtb);

        hipFuncSetAttribute((const void*)conv_mfma_kernel,
                            hipFuncAttributeMaxDynamicSharedMemorySize, 131072);
        conv_mfma_kernel<<<STOT / BN, THREADS, 131072, stream>>>(xp, wtb, bias, out);
    } else {
        long total = (long)NIMG * C_OUT * SP;
        conv_direct_kernel<<<(int)((total + 255) / 256), 256, 0, stream>>>(
            x, wgt, bias, out);
    }
}

// Round 3
// 87.876 us; speedup vs baseline: 1.3906x; 1.1762x over previous
//
#include <hip/hip_runtime.h>
#include <hip/hip_bf16.h>
#include <stdint.h>
#include <stddef.h>

// Problem constants
#define NIMG 32
#define C_IN 128
#define C_OUT 256
#define HW 56
#define SP 3136            // 56*56
#define STOT (NIMG * SP)   // 100352
#define PD 58              // padded spatial dim
#define KTOT 1152          // 128*9

// GEMM tiling
#define BM 256
#define BN 224             // 100352/224 = 448 blocks = 8*56 (XCD-exact)
#define BK 64
#define NKT (KTOT / BK)    // 18 K-tiles, 36 phases
#define THREADS 512

typedef __attribute__((ext_vector_type(8))) short bf16x8;
typedef __attribute__((ext_vector_type(4))) float f32x4;

__device__ __forceinline__ void gload16(const void* g, void* l) {
    __builtin_amdgcn_global_load_lds(
        (const __attribute__((address_space(1))) void*)g,
        (__attribute__((address_space(3))) void*)l,
        16, 0, 0);
}

#define BAR() do { asm volatile("" ::: "memory"); \
                   __builtin_amdgcn_s_barrier();  \
                   asm volatile("" ::: "memory"); } while (0)
#define LGKM(n) do { asm volatile("s_waitcnt lgkmcnt(" #n ")" ::: "memory"); \
                     __builtin_amdgcn_sched_barrier(0); } while (0)
#define VMCNT(n) do { asm volatile("s_waitcnt vmcnt(" #n ")" ::: "memory"); \
                      __builtin_amdgcn_sched_barrier(0); } while (0)

__device__ __forceinline__ unsigned short bf2u(float f) {
    __hip_bfloat16 b = __float2bfloat16(f);
    return *reinterpret_cast<unsigned short*>(&b);
}

// ---------------------------------------------------------------------------
// Prepass 1: NCHW fp32 -> padded NHWC bf16 [n][58][58][128], borders zeroed
// inline. One block per (n, padded row hp).  (BW-floor bound, ~12 us)
// ---------------------------------------------------------------------------
__global__ __launch_bounds__(256)
void pad_transpose_kernel(const float* __restrict__ x,
                          __hip_bfloat16* __restrict__ xp) {
    __shared__ float t[C_IN][HW + 1];
    const int hp = blockIdx.x % PD;
    const int n  = blockIdx.x / PD;
    const int h  = hp - 1;
    const bool interior = ((unsigned)h < (unsigned)HW);
    if (interior) {
        for (int idx = threadIdx.x; idx < C_IN * HW; idx += 256) {
            int ci = idx / HW, w = idx - ci * HW;
            t[ci][w] = x[((size_t)n * C_IN + ci) * SP + h * HW + w];
        }
    }
    __syncthreads();
    ushort4* dst = (ushort4*)(xp + ((size_t)n * PD + hp) * PD * C_IN);
    for (int idx = threadIdx.x; idx < PD * C_IN / 4; idx += 256) {
        int el = idx * 4;
        int wp = el >> 7, c0 = el & 127;
        ushort4 v = {0, 0, 0, 0};
        if (interior && wp >= 1 && wp <= HW) {
            int w = wp - 1;
            v.x = bf2u(t[c0 + 0][w]);
            v.y = bf2u(t[c0 + 1][w]);
            v.z = bf2u(t[c0 + 2][w]);
            v.w = bf2u(t[c0 + 3][w]);
        }
        dst[idx] = v;
    }
}

// ---------------------------------------------------------------------------
// Prepass 2: weight OIHW fp32 -> [tap][co][ci] bf16, tap = kh*3+kw
// ---------------------------------------------------------------------------
__global__ void wt_transform_kernel(const float* __restrict__ wgt,
                                    __hip_bfloat16* __restrict__ wt) {
    int idx = blockIdx.x * 256 + threadIdx.x;     // 294912 exact
    int ci  = idx & 127;
    int co  = (idx >> 7) & 255;
    int tap = idx >> 15;
    wt[idx] = __float2bfloat16(wgt[(co * C_IN + ci) * 9 + tap]);
}

// ---------------------------------------------------------------------------
// Main: implicit GEMM, 256x224 tile, BK=64, 8 waves (4M x 2N, 64x112 each).
// Software-pipelined phases: 36 phases (2 per K-tile), region ring of 4:
//   region[r], r = phase & 3; each = A[256x32] + B[256x32] bf16 (32 KB).
// Phase p: VMCNT(4); BAR; read frags(p+1); stage region[p+3]; LGKM(11);
//          28 MFMA on frags(p).  Stage->read distance = 2 phases; vmcnt(4)
//          retires exactly the stage issued 2 phases ago (4 loads/wave/stage,
//          uniform across waves via clamped dummy rows).
// ---------------------------------------------------------------------------
__global__ __launch_bounds__(THREADS, 2)
void conv_mfma_kernel(const __hip_bfloat16* __restrict__ xp,
                      const __hip_bfloat16* __restrict__ wt,
                      const float* __restrict__ bias,
                      float* __restrict__ out) {
    extern __shared__ short smem[];   // 4 regions * 16384 shorts = 128 KiB

    const int tid  = threadIdx.x;
    const int lane = tid & 63;
    const int wid  = tid >> 6;
    // XCD-bijective swizzle: 448 = 8 * 56
    const int wg   = (blockIdx.x & 7) * 56 + (blockIdx.x >> 3);
    const int s0   = wg * BN;

    // ---- staging constants (inverse-swizzled global source, rule #21) ----
    const int cg_el = (((lane & 3) ^ ((lane >> 3) & 3)) << 3);
    const int srow  = wid * 16 + (lane >> 2);        // 0..127
    const int aS0   = srow * C_IN + cg_el;           // A rows 0-127
    const int aS1   = aS0 + 128 * C_IN;              // A rows 128-255
    int s_r = s0 + srow;
    int n_  = s_r / SP, rem = s_r - n_ * SP;
    int h_  = rem / HW, w_ = rem - h_ * HW;
    const int bS0 = ((n_ * PD + h_) * PD + w_) * C_IN + cg_el;
    int srow2 = 128 + srow; if (srow2 > BN - 1) srow2 = BN - 1;  // clamp dummy
    s_r = s0 + srow2;
    n_ = s_r / SP; rem = s_r - n_ * SP; h_ = rem / HW; w_ = rem - h_ * HW;
    const int bS1 = ((n_ * PD + h_) * PD + w_) * C_IN + cg_el;
    const int ldsw = wid * 512;    // wave-uniform LDS dest (shorts)

    // ---- compute-phase read offsets (swizzled) ----
    const int rl  = lane & 15;
    const int rch = (((lane >> 4) ^ ((lane >> 1) & 3)) << 3);
    const int wm  = (wid >> 1) * 64;    // 4 M-waves
    const int wn  = (wid & 1) * 112;    // 2 N-waves
    const int aRd = (wm + rl) * 32 + rch;
    const int bRd = (wn + rl) * 32 + rch;

    auto STG = [&](int tau, int kk, int r) {
        int tap = tau >> 1;
        int ci0 = ((tau & 1) << 6) + (kk << 5);
        const __hip_bfloat16* wsrc = wt + tap * (C_OUT * C_IN) + ci0;
        short* Ad = smem + r * 16384 + ldsw;
        gload16(wsrc + aS0, Ad);
        gload16(wsrc + aS1, Ad + 4096);
        int kh = (tap * 11) >> 5, kw = tap - kh * 3;
        const __hip_bfloat16* xsrc = xp + (kh * PD + kw) * C_IN + ci0;
        short* Bd = smem + r * 16384 + 8192 + ldsw;
        gload16(xsrc + bS0, Bd);
        gload16(xsrc + bS1, Bd + 4096);
    };
    auto RD = [&](bf16x8* fa, bf16x8* fb, int r) {
        const short* Ab = smem + r * 16384;
        const short* Bb = Ab + 8192;
        #pragma unroll
        for (int j = 0; j < 4; ++j) fa[j] = *(const bf16x8*)(Ab + aRd + j * 512);
        #pragma unroll
        for (int j = 0; j < 7; ++j) fb[j] = *(const bf16x8*)(Bb + bRd + j * 512);
    };

    f32x4 acc[4][7] = {};
    bf16x8 fa0[4], fb0[7], fa1[4], fb1[7];

    #define MM(FA, FB) do { \
        __builtin_amdgcn_s_setprio(1); \
        _Pragma("unroll") \
        for (int mi = 0; mi < 4; ++mi) \
            _Pragma("unroll") \
            for (int ni = 0; ni < 7; ++ni) \
                acc[mi][ni] = __builtin_amdgcn_mfma_f32_16x16x32_bf16( \
                    FA[mi], FB[ni], acc[mi][ni], 0, 0, 0); \
        __builtin_amdgcn_s_setprio(0); \
    } while (0)

    // ---- prologue: regions 0,1,2 staged; frags(0) -> set0 ----
    STG(0, 0, 0); STG(0, 1, 1); STG(1, 0, 2);
    VMCNT(4);     // regions 0,1 landed
    BAR();
    RD(fa0, fb0, 0);

    for (int t = 0; t < NKT; ++t) {
        const int rb = (t & 1) << 1;   // base region this tile (0 or 2)

        // ---- phase A (p = 2t): MFMA set0; read set1<-region rb+1 ----
        VMCNT(4);
        BAR();
        RD(fa1, fb1, rb + 1);
        if (t <= 16) STG(t + 1, 1, (rb + 3) & 3);
        LGKM(11);
        MM(fa0, fb0);

        // ---- phase B (p = 2t+1): MFMA set1; read set0<-region (rb+2)&3 ----
        VMCNT(4);
        BAR();
        if (t <= 16) {
            RD(fa0, fb0, (rb + 2) & 3);
            if (t <= 15) STG(t + 2, 0, rb);
            LGKM(11);
        } else {
            LGKM(0);
        }
        MM(fa1, fb1);
    }
    #undef MM

    // ---- epilogue: D col = spatial (lane&15), row = co ----
    float bv[4][4];
    #pragma unroll
    for (int mi = 0; mi < 4; ++mi)
        #pragma unroll
        for (int j = 0; j < 4; ++j)
            bv[mi][j] = bias[wm + mi * 16 + ((lane >> 4) << 2) + j];

    #pragma unroll
    for (int ni = 0; ni < 7; ++ni) {
        int s  = s0 + wn + ni * 16 + rl;
        int n  = s / SP;
        int si = s - n * SP;
        float* obase = out + (size_t)n * C_OUT * SP + si;
        #pragma unroll
        for (int mi = 0; mi < 4; ++mi) {
            int cob = wm + mi * 16 + ((lane >> 4) << 2);
            #pragma unroll
            for (int j = 0; j < 4; ++j) {
                obase[(size_t)(cob + j) * SP] = acc[mi][ni][j] + bv[mi][j];
            }
        }
    }
}

// ---------------------------------------------------------------------------
// Fallback: direct fp32 conv (only if ws too small). Slow but correct.
// ---------------------------------------------------------------------------
__global__ void conv_direct_kernel(const float* __restrict__ x,
                                   const float* __restrict__ wgt,
                                   const float* __restrict__ bias,
                                   float* __restrict__ out) {
    long idx = (long)blockIdx.x * 256 + threadIdx.x;
    if (idx >= (long)NIMG * C_OUT * SP) return;
    int si = (int)(idx % SP);
    int co = (int)((idx / SP) % C_OUT);
    int n  = (int)(idx / ((long)SP * C_OUT));
    int h = si / HW, w = si - (si / HW) * HW;
    float acc = bias[co];
    for (int ci = 0; ci < C_IN; ++ci) {
        const float* xr = x + ((size_t)n * C_IN + ci) * SP;
        const float* wr = wgt + ((size_t)co * C_IN + ci) * 9;
        #pragma unroll
        for (int kh = 0; kh < 3; ++kh) {
            int ih = h + kh - 1;
            if (ih < 0 || ih >= HW) continue;
            #pragma unroll
            for (int kw = 0; kw < 3; ++kw) {
                int iw = w + kw - 1;
                if (iw < 0 || iw >= HW) continue;
                acc += xr[ih * HW + iw] * wr[kh * 3 + kw];
            }
        }
    }
    out[idx] = acc;
}

// ---------------------------------------------------------------------------
extern "C" void kernel_launch(void* const* d_in, const int* in_sizes, int n_in,
                              void* d_out, int out_size, void* d_ws, size_t ws_size,
                              hipStream_t stream) {
    const float* x    = (const float*)d_in[0];
    const float* wgt  = (const float*)d_in[1];
    const float* bias = (const float*)d_in[2];
    float* out = (float*)d_out;

    const size_t xp_bytes = (size_t)NIMG * PD * PD * C_IN * sizeof(__hip_bfloat16);
    const size_t wt_bytes = (size_t)9 * C_OUT * C_IN * sizeof(__hip_bfloat16);

    if (ws_size >= xp_bytes + wt_bytes) {
        __hip_bfloat16* xp  = (__hip_bfloat16*)d_ws;
        __hip_bfloat16* wtb = (__hip_bfloat16*)((char*)d_ws + xp_bytes);

        pad_transpose_kernel<<<NIMG * PD, 256, 0, stream>>>(x, xp);
        wt_transform_kernel<<<(9 * C_OUT * C_IN) / 256, 256, 0, stream>>>(wgt, wtb);

        hipFuncSetAttribute((const void*)conv_mfma_kernel,
                            hipFuncAttributeMaxDynamicSharedMemorySize, 131072);
        conv_mfma_kernel<<<STOT / BN, THREADS, 131072, stream>>>(xp, wtb, bias, out);
    } else {
        long total = (long)NIMG * C_OUT * SP;
        conv_direct_kernel<<<(int)((total + 255) / 256), 256, 0, stream>>>(
            x, wgt, bias, out);
    }
}